// Round 2
// baseline (313.048 us; speedup 1.0000x reference)
//
#include <hip/hip_runtime.h>

#define N_NODES 50000
#define IN_SIZE 512
#define HID 128
#define OUT 64
#define NB 256                 // edge-partition blocks (hist/scatter)
#define SHIFT 7                // bucket = dst >> 7  (128 nodes per bucket)
#define NBUCK 391              // ceil(50000/128)
#define NBINS8 12500           // 50000 uint8 bins packed in uint32 (50KB LDS)

typedef _Float16 f16x8 __attribute__((ext_vector_type(8)));
typedef _Float16 f16x4 __attribute__((ext_vector_type(4)));
typedef float    f32x4 __attribute__((ext_vector_type(4)));

// ---------- inline int64-vs-int32 layout detection (per block, no extra dispatch) ----------
__device__ __forceinline__ bool detect_w(const int* p, int t, int* sh) {
    if (t < 64) {
        unsigned long long m = __ballot(p[2 * t + 1] == 0);
        if (t == 0) *sh = (m == ~0ull) ? 1 : 0;
    }
    __syncthreads();
    return *sh != 0;
}

__device__ __forceinline__ int load_idx(const void* p, int e, bool w) {
    return w ? (int)((const long long*)p)[e] : ((const int*)p)[e];
}

// ---------- pass 1 (merged): coarse dst histogram + packed-u8 src histogram + weight transpose ----------
__global__ __launch_bounds__(256) void k_hist_wt(const void* __restrict__ srcp,
                                                 const void* __restrict__ dstp,
                                                 int* __restrict__ hist,
                                                 unsigned int* __restrict__ spart,
                                                 int E, int EPB,
                                                 const float* __restrict__ W1, _Float16* __restrict__ W1T,
                                                 const float* __restrict__ W2, _Float16* __restrict__ W2T) {
    const int t = threadIdx.x, b = blockIdx.x;
    if (b >= NB) {   // weight transpose tail blocks
        int i = (b - NB) * 256 + t;
        if (i < IN_SIZE * HID) {
            int k = i >> 7, n = i & (HID - 1);
            W1T[(size_t)n * IN_SIZE + k] = (_Float16)W1[i];
        } else {
            int j = i - IN_SIZE * HID;
            if (j < HID * OUT) {
                int k = j >> 6, n = j & (OUT - 1);
                W2T[(size_t)n * HID + k] = (_Float16)W2[j];
            }
        }
        return;
    }
    __shared__ unsigned int sbins[NBINS8];   // 50 KB
    __shared__ int dbins[NBUCK];             // 1.6 KB
    __shared__ int shw;
    for (int i = t; i < NBINS8; i += 256) sbins[i] = 0;
    for (int i = t; i < NBUCK; i += 256) dbins[i] = 0;
    bool w = detect_w((const int*)dstp, t, &shw);
    __syncthreads();
    int eend = min(E, (b + 1) * EPB);
    for (int e = b * EPB + t; e < eend; e += 256) {
        int s = load_idx(srcp, e, w);
        int d = load_idx(dstp, e, w);
        atomicAdd(&dbins[d >> SHIFT], 1);
        atomicAdd(&sbins[s >> 2], 1u << ((s & 3) << 3));
    }
    __syncthreads();
    for (int i = t; i < NBUCK; i += 256) hist[i * NB + b] = dbins[i];
    for (int i = t; i < NBINS8; i += 256) spart[(size_t)b * NBINS8 + i] = sbins[i];
}

// ---------- pass 2: scan hist (bucket-major) ----------
__global__ __launch_bounds__(256) void k_scanA(int* __restrict__ hist, int* __restrict__ bsum) {
    __shared__ int s[256];
    const int t = threadIdx.x, g = blockIdx.x;
    int v = hist[g * NB + t];
    s[t] = v;
    __syncthreads();
    for (int off = 1; off < 256; off <<= 1) {
        int u = (t >= off) ? s[t - off] : 0;
        __syncthreads();
        s[t] += u;
        __syncthreads();
    }
    hist[g * NB + t] = s[t] - v;
    if (t == 255) bsum[g] = s[255];
}

__global__ __launch_bounds__(512) void k_scanB(const int* __restrict__ bsum, int* __restrict__ bb) {
    __shared__ int s[512];
    const int t = threadIdx.x;
    int v = (t < NBUCK) ? bsum[t] : 0;
    s[t] = v;
    __syncthreads();
    for (int off = 1; off < 512; off <<= 1) {
        int u = (t >= off) ? s[t - off] : 0;
        __syncthreads();
        s[t] += u;
        __syncthreads();
    }
    if (t <= NBUCK) bb[t] = s[t] - v;     // bb[NBUCK] = total = E
}

// ---------- pass 3: coarse scatter, packed (src | dl<<16) ----------
__global__ __launch_bounds__(256) void k_cscatter(const void* __restrict__ srcp,
                                                  const void* __restrict__ dstp,
                                                  const int* __restrict__ hist,
                                                  const int* __restrict__ bb,
                                                  unsigned int* __restrict__ tmp,
                                                  int E, int EPB) {
    __shared__ int cur[NBUCK];
    __shared__ int shw;
    const int t = threadIdx.x, b = blockIdx.x;
    for (int i = t; i < NBUCK; i += 256) cur[i] = hist[i * NB + b] + bb[i];
    bool w = detect_w((const int*)dstp, t, &shw);
    __syncthreads();
    int eend = min(E, (b + 1) * EPB);
    for (int e = b * EPB + t; e < eend; e += 256) {
        int s = load_idx(srcp, e, w);
        int d = load_idx(dstp, e, w);
        int pos = atomicAdd(&cur[d >> SHIFT], 1);
        tmp[pos] = (unsigned int)s | ((unsigned int)(d & 127) << 16);
    }
}

// ---------- pass 4: fine count + scan + scatter; writes rp, innorm, onorm (u8 sred fused) ----------
__global__ __launch_bounds__(256) void k_fine(const unsigned int* __restrict__ tmp,
                                              const int* __restrict__ bb,
                                              const unsigned int* __restrict__ partial,
                                              int* __restrict__ rp,
                                              int* __restrict__ esrc,
                                              float* __restrict__ innorm,
                                              float* __restrict__ onorm) {
    __shared__ int fcnt[128];
    __shared__ int sc[128];
    __shared__ int fcur[128];
    __shared__ int rs[256][4];
    const int t = threadIdx.x, u = blockIdx.x;
    const int e0 = bb[u], e1 = bb[u + 1];
    if (t < 128) fcnt[t] = 0;
    __syncthreads();
    for (int e = e0 + t; e < e1; e += 256)
        atomicAdd(&fcnt[tmp[e] >> 16], 1);
    // fused sred (all 256 threads): bucket u owns packed words u*32 .. u*32+31 (4 nodes/word).
    {
        const int wrd = t & 31, grp = t >> 5;
        const int wd = u * 32 + wrd;
        int c0 = 0, c1 = 0, c2 = 0, c3 = 0;
        if (wd < NBINS8) {
            for (int b = grp * 32; b < grp * 32 + 32; ++b) {
                unsigned int v = partial[(size_t)b * NBINS8 + wd];
                c0 += (int)(v & 255u);
                c1 += (int)((v >> 8) & 255u);
                c2 += (int)((v >> 16) & 255u);
                c3 += (int)(v >> 24);
            }
        }
        rs[t][0] = c0; rs[t][1] = c1; rs[t][2] = c2; rs[t][3] = c3;
    }
    __syncthreads();   // covers fcnt atomics AND rs
    if (t < 32) {
        const int wd = u * 32 + t;
        if (wd < NBINS8) {
            int d0 = 0, d1 = 0, d2 = 0, d3 = 0;
            for (int g = 0; g < 8; ++g) {
                d0 += rs[g * 32 + t][0]; d1 += rs[g * 32 + t][1];
                d2 += rs[g * 32 + t][2]; d3 += rs[g * 32 + t][3];
            }
            if (d0 < 1) d0 = 1; if (d1 < 1) d1 = 1;
            if (d2 < 1) d2 = 1; if (d3 < 1) d3 = 1;
            int n0 = 4 * wd;
            if (n0     < N_NODES) onorm[n0]     = 1.0f / sqrtf((float)d0);
            if (n0 + 1 < N_NODES) onorm[n0 + 1] = 1.0f / sqrtf((float)d1);
            if (n0 + 2 < N_NODES) onorm[n0 + 2] = 1.0f / sqrtf((float)d2);
            if (n0 + 3 < N_NODES) onorm[n0 + 3] = 1.0f / sqrtf((float)d3);
        }
    }
    if (t < 128) sc[t] = fcnt[t];
    __syncthreads();
    for (int off = 1; off < 128; off <<= 1) {
        int v = (t < 128 && t >= off) ? sc[t - off] : 0;
        __syncthreads();
        if (t < 128) sc[t] += v;
        __syncthreads();
    }
    if (t < 128) {
        int base = e0 + sc[t] - fcnt[t];
        fcur[t] = base;
        int node = u * 128 + t;
        if (node < N_NODES) {
            rp[node] = base;
            int c = fcnt[t]; if (c < 1) c = 1;
            innorm[node] = 1.0f / sqrtf((float)c);
        }
    }
    if (u == NBUCK - 1 && t == 0) rp[N_NODES] = e1;
    __syncthreads();
    for (int e = e0 + t; e < e1; e += 256) {
        unsigned int p = tmp[e];
        int pos = atomicAdd(&fcur[p >> 16], 1);
        esrc[pos] = (int)(p & 0xFFFFu);
    }
}

// ---------- GEMM1 (MFMA fp16, no LDS / no barriers): X1[n,:] = fp16( onorm[n] * (feat[n,:] @ W1) ) ----------
// Direct global fragment loads. A-frag: lanes {lm, lq=0..3} jointly cover one contiguous 128B
// span of row (row0+wave*16+lm) -> two fully line-covering global_load_dwordx4 per lane.
// B-frags hit W1T (128KB, L2-resident; 4 waves in lockstep -> L1 reuse).
// Fragment indexing identical to the previous LDS version by construction:
//   As[r*LDA+j] == A[(row0+r)*512 + k0 + j],  Bs[r*LDA+j] == BT[r*512 + k0 + j].
__global__ __launch_bounds__(256) void k_gemm1_mfma(const float* __restrict__ A,
                                                    const _Float16* __restrict__ BT,
                                                    const float* __restrict__ onorm,
                                                    _Float16* __restrict__ X) {
    const int tid  = threadIdx.x;
    const int wave = tid >> 6, lane = tid & 63;
    const int lm = lane & 15, lq = lane >> 4;
    const int row0 = blockIdx.x * 64;

    int arow = row0 + wave * 16 + lm;
    if (arow >= N_NODES) arow = N_NODES - 1;
    const float* aptr = A + (size_t)arow * IN_SIZE + lq * 8;
    const _Float16* bptr = BT + (size_t)lm * IN_SIZE + lq * 8;

    f32x4 acc[8];
#pragma unroll
    for (int nt = 0; nt < 8; ++nt) acc[nt] = (f32x4){0.f, 0.f, 0.f, 0.f};

#pragma unroll 2
    for (int k0 = 0; k0 < IN_SIZE; k0 += 32) {
        float4 a0 = *(const float4*)(aptr + k0);
        float4 a1 = *(const float4*)(aptr + k0 + 4);
        f16x8 af = {(_Float16)a0.x, (_Float16)a0.y, (_Float16)a0.z, (_Float16)a0.w,
                    (_Float16)a1.x, (_Float16)a1.y, (_Float16)a1.z, (_Float16)a1.w};
#pragma unroll
        for (int nt = 0; nt < 8; ++nt) {
            f16x8 bf = *(const f16x8*)(bptr + (size_t)nt * 16 * IN_SIZE + k0);
            acc[nt] = __builtin_amdgcn_mfma_f32_16x16x32_f16(af, bf, acc[nt], 0, 0, 0);
        }
    }
#pragma unroll
    for (int i = 0; i < 4; ++i) {
        int row = row0 + wave * 16 + lq * 4 + i;
        if (row < N_NODES) {
            float on = onorm[row];
            _Float16* o = X + (size_t)row * HID + lm;
#pragma unroll
            for (int nt = 0; nt < 8; ++nt)
                o[nt * 16] = (_Float16)(acc[nt][i] * on);
        }
    }
}

// ---------- agg1 + fused GEMM2: X2 = fp16( H @ W2 ),  H = relu(gather(X1)*innorm + b1)*onorm ----------
#define LDH 136  // 128 + 8 halfs pad
__global__ __launch_bounds__(256) void k_agg1_fused(const _Float16* __restrict__ X, const int* __restrict__ rp,
                                                    const int* __restrict__ esrc, const float* __restrict__ innorm,
                                                    const float* __restrict__ onorm, const float* __restrict__ b1,
                                                    const _Float16* __restrict__ W2T, _Float16* __restrict__ X2) {
    __shared__ _Float16 Hs[16 * LDH];
    const int t = threadIdx.x;
    const int ln = t >> 4;           // local node 0..15
    const int c  = (t & 15) << 3;    // col 0..120 step 8
    const int n  = blockIdx.x * 16 + ln;   // grid exact: 3125*16 == 50000
    const int e0 = rp[n], e1 = rp[n + 1];
    float a[8] = {0.f, 0.f, 0.f, 0.f, 0.f, 0.f, 0.f, 0.f};
    int e = e0;
    for (; e + 3 < e1; e += 4) {
        int s0 = esrc[e], s1 = esrc[e + 1], s2 = esrc[e + 2], s3 = esrc[e + 3];
        f16x8 v0 = *(const f16x8*)&X[(size_t)s0 * HID + c];
        f16x8 v1 = *(const f16x8*)&X[(size_t)s1 * HID + c];
        f16x8 v2 = *(const f16x8*)&X[(size_t)s2 * HID + c];
        f16x8 v3 = *(const f16x8*)&X[(size_t)s3 * HID + c];
#pragma unroll
        for (int j = 0; j < 8; ++j)
            a[j] += ((float)v0[j] + (float)v1[j]) + ((float)v2[j] + (float)v3[j]);
    }
    for (; e < e1; ++e) {
        f16x8 v = *(const f16x8*)&X[(size_t)esrc[e] * HID + c];
#pragma unroll
        for (int j = 0; j < 8; ++j) a[j] += (float)v[j];
    }
    const float inn = innorm[n], on = onorm[n];
    float4 bA = *(const float4*)&b1[c];
    float4 bB = *(const float4*)&b1[c + 4];
    const float bv[8] = {bA.x, bA.y, bA.z, bA.w, bB.x, bB.y, bB.z, bB.w};
    f16x8 h;
#pragma unroll
    for (int j = 0; j < 8; ++j)
        h[j] = (_Float16)(fmaxf(a[j] * inn + bv[j], 0.f) * on);
    *(f16x8*)&Hs[ln * LDH + c] = h;
    __syncthreads();

    // fused 16x128 @ 128x64: wave w owns output cols w*16..w*16+15 over the block's 16 nodes
    const int wave = t >> 6, lane = t & 63;
    const int lm = lane & 15, lq = lane >> 4;
    f32x4 acc = (f32x4){0.f, 0.f, 0.f, 0.f};
#pragma unroll
    for (int k0 = 0; k0 < HID; k0 += 32) {
        f16x8 af = *(const f16x8*)&Hs[lm * LDH + k0 + lq * 8];
        f16x8 bf = *(const f16x8*)&W2T[(size_t)(wave * 16 + lm) * HID + k0 + lq * 8];
        acc = __builtin_amdgcn_mfma_f32_16x16x32_f16(af, bf, acc, 0, 0, 0);
    }
    const int n0 = blockIdx.x * 16;
#pragma unroll
    for (int i = 0; i < 4; ++i) {
        int row = n0 + lq * 4 + i;
        X2[(size_t)row * OUT + wave * 16 + lm] = (_Float16)acc[i];
    }
}

// ---------- agg2: out = gather-sum(X2)*in_norm + b2  (fp32 out) ----------
__global__ __launch_bounds__(256) void k_agg2(const _Float16* __restrict__ X2, const int* __restrict__ rp,
                                              const int* __restrict__ esrc, const float* __restrict__ innorm,
                                              const float* __restrict__ b2, float* __restrict__ out) {
    const int n = blockIdx.x * 32 + (threadIdx.x >> 3);
    const int c = (threadIdx.x & 7) << 3;
    if (n >= N_NODES) return;
    const int e0 = rp[n], e1 = rp[n + 1];
    float a[8] = {0.f, 0.f, 0.f, 0.f, 0.f, 0.f, 0.f, 0.f};
    int e = e0;
    for (; e + 3 < e1; e += 4) {
        int s0 = esrc[e], s1 = esrc[e + 1], s2 = esrc[e + 2], s3 = esrc[e + 3];
        f16x8 v0 = *(const f16x8*)&X2[(size_t)s0 * OUT + c];
        f16x8 v1 = *(const f16x8*)&X2[(size_t)s1 * OUT + c];
        f16x8 v2 = *(const f16x8*)&X2[(size_t)s2 * OUT + c];
        f16x8 v3 = *(const f16x8*)&X2[(size_t)s3 * OUT + c];
#pragma unroll
        for (int j = 0; j < 8; ++j)
            a[j] += ((float)v0[j] + (float)v1[j]) + ((float)v2[j] + (float)v3[j]);
    }
    for (; e < e1; ++e) {
        f16x8 v = *(const f16x8*)&X2[(size_t)esrc[e] * OUT + c];
#pragma unroll
        for (int j = 0; j < 8; ++j) a[j] += (float)v[j];
    }
    const float inn = innorm[n];
    float4 bA = *(const float4*)&b2[c];
    float4 bB = *(const float4*)&b2[c + 4];
    float* o = out + (size_t)n * OUT + c;
    *(float4*)o       = make_float4(a[0] * inn + bA.x, a[1] * inn + bA.y,
                                    a[2] * inn + bA.z, a[3] * inn + bA.w);
    *(float4*)(o + 4) = make_float4(a[4] * inn + bB.x, a[5] * inn + bB.y,
                                    a[6] * inn + bB.z, a[7] * inn + bB.w);
}

extern "C" void kernel_launch(void* const* d_in, const int* in_sizes, int n_in,
                              void* d_out, int out_size, void* d_ws, size_t ws_size,
                              hipStream_t stream) {
    const float* feat = (const float*)d_in[0];
    const float* W1   = (const float*)d_in[1];
    const float* b1   = (const float*)d_in[2];
    const float* W2   = (const float*)d_in[3];
    const float* b2   = (const float*)d_in[4];
    const void*  srcp = (const void*)d_in[5];
    const void*  dstp = (const void*)d_in[6];
    const int    E    = in_sizes[5];
    float* out = (float*)d_out;

    char* w = (char*)d_ws;
    size_t off = 0;
    auto alloc = [&](size_t bytes) -> void* {
        off = (off + 255) & ~(size_t)255;
        void* p = w + off;
        off += bytes;
        return p;
    };
    int*   hist    = (int*)alloc((size_t)NBUCK * NB * 4);
    int*   bsum    = (int*)alloc((size_t)NBUCK * 4);
    int*   bb      = (int*)alloc((size_t)(NBUCK + 1) * 4);
    int*   rp      = (int*)alloc((size_t)(N_NODES + 1) * 4);
    unsigned int* spart = (unsigned int*)alloc((size_t)NB * NBINS8 * 4);
    unsigned int* tmp   = (unsigned int*)alloc((size_t)E * 4);
    int*   esrc    = (int*)alloc((size_t)E * 4);
    float* onorm   = (float*)alloc((size_t)N_NODES * 4);
    float* innorm  = (float*)alloc((size_t)N_NODES * 4);
    _Float16* W1T  = (_Float16*)alloc((size_t)IN_SIZE * HID * 2);
    _Float16* W2T  = (_Float16*)alloc((size_t)HID * OUT * 2);
    _Float16* X1   = (_Float16*)alloc((size_t)N_NODES * HID * 2);
    _Float16* X2   = (_Float16*)alloc((size_t)N_NODES * OUT * 2);
    (void)ws_size; (void)n_in; (void)out_size;

    const int EPB = (E + NB - 1) / NB;
    const int WTB = (IN_SIZE * HID + HID * OUT + 255) / 256;

    // CSR build — no global atomics anywhere
    k_hist_wt<<<NB + WTB, 256, 0, stream>>>(srcp, dstp, hist, spart, E, EPB, W1, W1T, W2, W2T);
    k_scanA<<<NBUCK, 256, 0, stream>>>(hist, bsum);
    k_scanB<<<1, 512, 0, stream>>>(bsum, bb);
    k_cscatter<<<NB, 256, 0, stream>>>(srcp, dstp, hist, bb, tmp, E, EPB);
    k_fine<<<NBUCK, 256, 0, stream>>>(tmp, bb, spart, rp, esrc, innorm, onorm);

    // dense + aggregation pipeline (gemm2 fused into agg1 epilogue)
    k_gemm1_mfma<<<(N_NODES + 63) / 64, 256, 0, stream>>>(feat, W1T, onorm, X1);
    k_agg1_fused<<<(N_NODES + 15) / 16, 256, 0, stream>>>(X1, rp, esrc, innorm, onorm, b1, W2T, X2);
    k_agg2<<<(N_NODES + 31) / 32, 256, 0, stream>>>(X2, rp, esrc, innorm, b2, out);
}

// Round 3
// 271.735 us; speedup vs baseline: 1.1520x; 1.1520x over previous
//
#include <hip/hip_runtime.h>

#define N_NODES 50000
#define IN_SIZE 512
#define HID 128
#define OUT 64
#define NB 256                 // edge-partition blocks (hist/scatter)
#define SHIFT 7                // bucket = dst >> 7  (128 nodes per bucket)
#define NBUCK 391              // ceil(50000/128)
#define NBINS8 12500           // 50000 uint8 bins packed in uint32 (50KB LDS)

typedef _Float16 f16x8 __attribute__((ext_vector_type(8)));
typedef _Float16 f16x4 __attribute__((ext_vector_type(4)));
typedef float    f32x4 __attribute__((ext_vector_type(4)));

// ---------- inline int64-vs-int32 layout detection (per block, no extra dispatch) ----------
__device__ __forceinline__ bool detect_w(const int* p, int t, int* sh) {
    if (t < 64) {
        unsigned long long m = __ballot(p[2 * t + 1] == 0);
        if (t == 0) *sh = (m == ~0ull) ? 1 : 0;
    }
    __syncthreads();
    return *sh != 0;
}

__device__ __forceinline__ int load_idx(const void* p, int e, bool w) {
    return w ? (int)((const long long*)p)[e] : ((const int*)p)[e];
}

// ---------- pass 1 (merged): coarse dst histogram + packed-u8 src histogram + weight transpose ----------
__global__ __launch_bounds__(256) void k_hist_wt(const void* __restrict__ srcp,
                                                 const void* __restrict__ dstp,
                                                 int* __restrict__ hist,
                                                 unsigned int* __restrict__ spart,
                                                 int E, int EPB,
                                                 const float* __restrict__ W1, _Float16* __restrict__ W1T,
                                                 const float* __restrict__ W2, _Float16* __restrict__ W2T) {
    const int t = threadIdx.x, b = blockIdx.x;
    if (b >= NB) {   // weight transpose tail blocks
        int i = (b - NB) * 256 + t;
        if (i < IN_SIZE * HID) {
            int k = i >> 7, n = i & (HID - 1);
            W1T[(size_t)n * IN_SIZE + k] = (_Float16)W1[i];
        } else {
            int j = i - IN_SIZE * HID;
            if (j < HID * OUT) {
                int k = j >> 6, n = j & (OUT - 1);
                W2T[(size_t)n * HID + k] = (_Float16)W2[j];
            }
        }
        return;
    }
    __shared__ unsigned int sbins[NBINS8];   // 50 KB
    __shared__ int dbins[NBUCK];             // 1.6 KB
    __shared__ int shw;
    for (int i = t; i < NBINS8; i += 256) sbins[i] = 0;
    for (int i = t; i < NBUCK; i += 256) dbins[i] = 0;
    bool w = detect_w((const int*)dstp, t, &shw);
    __syncthreads();
    int eend = min(E, (b + 1) * EPB);
    for (int e = b * EPB + t; e < eend; e += 256) {
        int s = load_idx(srcp, e, w);
        int d = load_idx(dstp, e, w);
        atomicAdd(&dbins[d >> SHIFT], 1);
        atomicAdd(&sbins[s >> 2], 1u << ((s & 3) << 3));
    }
    __syncthreads();
    for (int i = t; i < NBUCK; i += 256) hist[i * NB + b] = dbins[i];
    for (int i = t; i < NBINS8; i += 256) spart[(size_t)b * NBINS8 + i] = sbins[i];
}

// ---------- pass 2: scan hist (bucket-major) ----------
__global__ __launch_bounds__(256) void k_scanA(int* __restrict__ hist, int* __restrict__ bsum) {
    __shared__ int s[256];
    const int t = threadIdx.x, g = blockIdx.x;
    int v = hist[g * NB + t];
    s[t] = v;
    __syncthreads();
    for (int off = 1; off < 256; off <<= 1) {
        int u = (t >= off) ? s[t - off] : 0;
        __syncthreads();
        s[t] += u;
        __syncthreads();
    }
    hist[g * NB + t] = s[t] - v;
    if (t == 255) bsum[g] = s[255];
}

__global__ __launch_bounds__(512) void k_scanB(const int* __restrict__ bsum, int* __restrict__ bb) {
    __shared__ int s[512];
    const int t = threadIdx.x;
    int v = (t < NBUCK) ? bsum[t] : 0;
    s[t] = v;
    __syncthreads();
    for (int off = 1; off < 512; off <<= 1) {
        int u = (t >= off) ? s[t - off] : 0;
        __syncthreads();
        s[t] += u;
        __syncthreads();
    }
    if (t <= NBUCK) bb[t] = s[t] - v;     // bb[NBUCK] = total = E
}

// ---------- pass 3: coarse scatter, packed (src | dl<<16) ----------
__global__ __launch_bounds__(256) void k_cscatter(const void* __restrict__ srcp,
                                                  const void* __restrict__ dstp,
                                                  const int* __restrict__ hist,
                                                  const int* __restrict__ bb,
                                                  unsigned int* __restrict__ tmp,
                                                  int E, int EPB) {
    __shared__ int cur[NBUCK];
    __shared__ int shw;
    const int t = threadIdx.x, b = blockIdx.x;
    for (int i = t; i < NBUCK; i += 256) cur[i] = hist[i * NB + b] + bb[i];
    bool w = detect_w((const int*)dstp, t, &shw);
    __syncthreads();
    int eend = min(E, (b + 1) * EPB);
    for (int e = b * EPB + t; e < eend; e += 256) {
        int s = load_idx(srcp, e, w);
        int d = load_idx(dstp, e, w);
        int pos = atomicAdd(&cur[d >> SHIFT], 1);
        tmp[pos] = (unsigned int)s | ((unsigned int)(d & 127) << 16);
    }
}

// ---------- pass 4: fine count + scan + scatter; writes rp, innorm, onorm (u8 sred fused) ----------
__global__ __launch_bounds__(256) void k_fine(const unsigned int* __restrict__ tmp,
                                              const int* __restrict__ bb,
                                              const unsigned int* __restrict__ partial,
                                              int* __restrict__ rp,
                                              int* __restrict__ esrc,
                                              float* __restrict__ innorm,
                                              float* __restrict__ onorm) {
    __shared__ int fcnt[128];
    __shared__ int sc[128];
    __shared__ int fcur[128];
    __shared__ int rs[256][4];
    const int t = threadIdx.x, u = blockIdx.x;
    const int e0 = bb[u], e1 = bb[u + 1];
    if (t < 128) fcnt[t] = 0;
    __syncthreads();
    for (int e = e0 + t; e < e1; e += 256)
        atomicAdd(&fcnt[tmp[e] >> 16], 1);
    // fused sred (all 256 threads): bucket u owns packed words u*32 .. u*32+31 (4 nodes/word).
    {
        const int wrd = t & 31, grp = t >> 5;
        const int wd = u * 32 + wrd;
        int c0 = 0, c1 = 0, c2 = 0, c3 = 0;
        if (wd < NBINS8) {
            for (int b = grp * 32; b < grp * 32 + 32; ++b) {
                unsigned int v = partial[(size_t)b * NBINS8 + wd];
                c0 += (int)(v & 255u);
                c1 += (int)((v >> 8) & 255u);
                c2 += (int)((v >> 16) & 255u);
                c3 += (int)(v >> 24);
            }
        }
        rs[t][0] = c0; rs[t][1] = c1; rs[t][2] = c2; rs[t][3] = c3;
    }
    __syncthreads();   // covers fcnt atomics AND rs
    if (t < 32) {
        const int wd = u * 32 + t;
        if (wd < NBINS8) {
            int d0 = 0, d1 = 0, d2 = 0, d3 = 0;
            for (int g = 0; g < 8; ++g) {
                d0 += rs[g * 32 + t][0]; d1 += rs[g * 32 + t][1];
                d2 += rs[g * 32 + t][2]; d3 += rs[g * 32 + t][3];
            }
            if (d0 < 1) d0 = 1; if (d1 < 1) d1 = 1;
            if (d2 < 1) d2 = 1; if (d3 < 1) d3 = 1;
            int n0 = 4 * wd;
            if (n0     < N_NODES) onorm[n0]     = 1.0f / sqrtf((float)d0);
            if (n0 + 1 < N_NODES) onorm[n0 + 1] = 1.0f / sqrtf((float)d1);
            if (n0 + 2 < N_NODES) onorm[n0 + 2] = 1.0f / sqrtf((float)d2);
            if (n0 + 3 < N_NODES) onorm[n0 + 3] = 1.0f / sqrtf((float)d3);
        }
    }
    if (t < 128) sc[t] = fcnt[t];
    __syncthreads();
    for (int off = 1; off < 128; off <<= 1) {
        int v = (t < 128 && t >= off) ? sc[t - off] : 0;
        __syncthreads();
        if (t < 128) sc[t] += v;
        __syncthreads();
    }
    if (t < 128) {
        int base = e0 + sc[t] - fcnt[t];
        fcur[t] = base;
        int node = u * 128 + t;
        if (node < N_NODES) {
            rp[node] = base;
            int c = fcnt[t]; if (c < 1) c = 1;
            innorm[node] = 1.0f / sqrtf((float)c);
        }
    }
    if (u == NBUCK - 1 && t == 0) rp[N_NODES] = e1;
    __syncthreads();
    for (int e = e0 + t; e < e1; e += 256) {
        unsigned int p = tmp[e];
        int pos = atomicAdd(&fcur[p >> 16], 1);
        esrc[pos] = (int)(p & 0xFFFFu);
    }
}

// ---------- GEMM1 (MFMA fp16, double-buffered LDS): X1[n,:] = fp16( onorm[n] * (feat[n,:] @ W1) ) ----------
// 2-phase schedule: issue next tile's global loads FIRST, MFMA current LDS buffer while they fly,
// then write the other buffer + ONE barrier per K-step. LDA=44: 16 fragment rows -> 16 distinct
// 128B phase offsets (LDA=40 aliased row pairs -> 3.0M bank-conflict cycles in R1).
#define LDA 44  // 32 + 12 halfs pad
__global__ __launch_bounds__(256) void k_gemm1_mfma(const float* __restrict__ A,
                                                    const _Float16* __restrict__ BT,
                                                    const float* __restrict__ onorm,
                                                    _Float16* __restrict__ X) {
    __shared__ _Float16 As[2][64 * LDA];
    __shared__ _Float16 Bs[2][128 * LDA];
    const int tid  = threadIdx.x;
    const int wave = tid >> 6, lane = tid & 63;
    const int lm = lane & 15, lq = lane >> 4;
    const int row0 = blockIdx.x * 64;

    const int ar = tid >> 2, aq = tid & 3;
    int arow = row0 + ar; if (arow >= N_NODES) arow = N_NODES - 1;
    const float* aptr = A + (size_t)arow * IN_SIZE + aq * 8;
    const int bn = tid >> 1, bh = tid & 1;
    const _Float16* bptr = BT + (size_t)bn * IN_SIZE + bh * 16;

    f32x4 acc[8];
#pragma unroll
    for (int nt = 0; nt < 8; ++nt) acc[nt] = (f32x4){0.f, 0.f, 0.f, 0.f};

    // prologue: stage tile 0 into buffer 0
    {
        float4 a0 = *(const float4*)(aptr);
        float4 a1 = *(const float4*)(aptr + 4);
        f16x8  b0 = *(const f16x8*)(bptr);
        f16x8  b1 = *(const f16x8*)(bptr + 8);
        f16x8 ap = {(_Float16)a0.x, (_Float16)a0.y, (_Float16)a0.z, (_Float16)a0.w,
                    (_Float16)a1.x, (_Float16)a1.y, (_Float16)a1.z, (_Float16)a1.w};
        *(f16x8*)&As[0][ar * LDA + aq * 8]      = ap;
        *(f16x8*)&Bs[0][bn * LDA + bh * 16]     = b0;
        *(f16x8*)&Bs[0][bn * LDA + bh * 16 + 8] = b1;
    }
    __syncthreads();

#pragma unroll
    for (int kt = 0; kt < IN_SIZE / 32; ++kt) {
        const int k0 = kt * 32;
        const int cur = kt & 1;
        // issue next tile's global loads (in flight during the MFMAs below)
        float4 na0, na1; f16x8 nb0, nb1;
        const bool more = (k0 + 32) < IN_SIZE;
        if (more) {
            na0 = *(const float4*)(aptr + k0 + 32);
            na1 = *(const float4*)(aptr + k0 + 36);
            nb0 = *(const f16x8*)(bptr + k0 + 32);
            nb1 = *(const f16x8*)(bptr + k0 + 40);
        }
        // compute current buffer
        f16x8 af = *(const f16x8*)&As[cur][(wave * 16 + lm) * LDA + lq * 8];
#pragma unroll
        for (int nt = 0; nt < 8; ++nt) {
            f16x8 bf = *(const f16x8*)&Bs[cur][(nt * 16 + lm) * LDA + lq * 8];
            acc[nt] = __builtin_amdgcn_mfma_f32_16x16x32_f16(af, bf, acc[nt], 0, 0, 0);
        }
        // write-late into the other buffer, single barrier
        if (more) {
            f16x8 ap = {(_Float16)na0.x, (_Float16)na0.y, (_Float16)na0.z, (_Float16)na0.w,
                        (_Float16)na1.x, (_Float16)na1.y, (_Float16)na1.z, (_Float16)na1.w};
            *(f16x8*)&As[cur ^ 1][ar * LDA + aq * 8]      = ap;
            *(f16x8*)&Bs[cur ^ 1][bn * LDA + bh * 16]     = nb0;
            *(f16x8*)&Bs[cur ^ 1][bn * LDA + bh * 16 + 8] = nb1;
            __syncthreads();
        }
    }
#pragma unroll
    for (int i = 0; i < 4; ++i) {
        int row = row0 + wave * 16 + lq * 4 + i;
        if (row < N_NODES) {
            float on = onorm[row];
            _Float16* o = X + (size_t)row * HID + lm;
#pragma unroll
            for (int nt = 0; nt < 8; ++nt)
                o[nt * 16] = (_Float16)(acc[nt][i] * on);
        }
    }
}

// ---------- agg1 + fused GEMM2: X2 = fp16( H @ W2 ),  H = relu(gather(X1)*innorm + b1)*onorm ----------
#define LDH 136  // 128 + 8 halfs pad
__global__ __launch_bounds__(256) void k_agg1_fused(const _Float16* __restrict__ X, const int* __restrict__ rp,
                                                    const int* __restrict__ esrc, const float* __restrict__ innorm,
                                                    const float* __restrict__ onorm, const float* __restrict__ b1,
                                                    const _Float16* __restrict__ W2T, _Float16* __restrict__ X2) {
    __shared__ _Float16 Hs[16 * LDH];
    const int t = threadIdx.x;
    const int ln = t >> 4;           // local node 0..15
    const int c  = (t & 15) << 3;    // col 0..120 step 8
    const int n  = blockIdx.x * 16 + ln;   // grid exact: 3125*16 == 50000
    const int e0 = rp[n], e1 = rp[n + 1];
    float a[8] = {0.f, 0.f, 0.f, 0.f, 0.f, 0.f, 0.f, 0.f};
    int e = e0;
    for (; e + 3 < e1; e += 4) {
        int s0 = esrc[e], s1 = esrc[e + 1], s2 = esrc[e + 2], s3 = esrc[e + 3];
        f16x8 v0 = *(const f16x8*)&X[(size_t)s0 * HID + c];
        f16x8 v1 = *(const f16x8*)&X[(size_t)s1 * HID + c];
        f16x8 v2 = *(const f16x8*)&X[(size_t)s2 * HID + c];
        f16x8 v3 = *(const f16x8*)&X[(size_t)s3 * HID + c];
#pragma unroll
        for (int j = 0; j < 8; ++j)
            a[j] += ((float)v0[j] + (float)v1[j]) + ((float)v2[j] + (float)v3[j]);
    }
    for (; e < e1; ++e) {
        f16x8 v = *(const f16x8*)&X[(size_t)esrc[e] * HID + c];
#pragma unroll
        for (int j = 0; j < 8; ++j) a[j] += (float)v[j];
    }
    const float inn = innorm[n], on = onorm[n];
    float4 bA = *(const float4*)&b1[c];
    float4 bB = *(const float4*)&b1[c + 4];
    const float bv[8] = {bA.x, bA.y, bA.z, bA.w, bB.x, bB.y, bB.z, bB.w};
    f16x8 h;
#pragma unroll
    for (int j = 0; j < 8; ++j)
        h[j] = (_Float16)(fmaxf(a[j] * inn + bv[j], 0.f) * on);
    *(f16x8*)&Hs[ln * LDH + c] = h;
    __syncthreads();

    // fused 16x128 @ 128x64: wave w owns output cols w*16..w*16+15 over the block's 16 nodes
    const int wave = t >> 6, lane = t & 63;
    const int lm = lane & 15, lq = lane >> 4;
    f32x4 acc = (f32x4){0.f, 0.f, 0.f, 0.f};
#pragma unroll
    for (int k0 = 0; k0 < HID; k0 += 32) {
        f16x8 af = *(const f16x8*)&Hs[lm * LDH + k0 + lq * 8];
        f16x8 bf = *(const f16x8*)&W2T[(size_t)(wave * 16 + lm) * HID + k0 + lq * 8];
        acc = __builtin_amdgcn_mfma_f32_16x16x32_f16(af, bf, acc, 0, 0, 0);
    }
    const int n0 = blockIdx.x * 16;
#pragma unroll
    for (int i = 0; i < 4; ++i) {
        int row = n0 + lq * 4 + i;
        X2[(size_t)row * OUT + wave * 16 + lm] = (_Float16)acc[i];
    }
}

// ---------- agg2: out = gather-sum(X2)*in_norm + b2  (fp32 out) ----------
__global__ __launch_bounds__(256) void k_agg2(const _Float16* __restrict__ X2, const int* __restrict__ rp,
                                              const int* __restrict__ esrc, const float* __restrict__ innorm,
                                              const float* __restrict__ b2, float* __restrict__ out) {
    const int n = blockIdx.x * 32 + (threadIdx.x >> 3);
    const int c = (threadIdx.x & 7) << 3;
    if (n >= N_NODES) return;
    const int e0 = rp[n], e1 = rp[n + 1];
    float a[8] = {0.f, 0.f, 0.f, 0.f, 0.f, 0.f, 0.f, 0.f};
    int e = e0;
    for (; e + 3 < e1; e += 4) {
        int s0 = esrc[e], s1 = esrc[e + 1], s2 = esrc[e + 2], s3 = esrc[e + 3];
        f16x8 v0 = *(const f16x8*)&X2[(size_t)s0 * OUT + c];
        f16x8 v1 = *(const f16x8*)&X2[(size_t)s1 * OUT + c];
        f16x8 v2 = *(const f16x8*)&X2[(size_t)s2 * OUT + c];
        f16x8 v3 = *(const f16x8*)&X2[(size_t)s3 * OUT + c];
#pragma unroll
        for (int j = 0; j < 8; ++j)
            a[j] += ((float)v0[j] + (float)v1[j]) + ((float)v2[j] + (float)v3[j]);
    }
    for (; e < e1; ++e) {
        f16x8 v = *(const f16x8*)&X2[(size_t)esrc[e] * OUT + c];
#pragma unroll
        for (int j = 0; j < 8; ++j) a[j] += (float)v[j];
    }
    const float inn = innorm[n];
    float4 bA = *(const float4*)&b2[c];
    float4 bB = *(const float4*)&b2[c + 4];
    float* o = out + (size_t)n * OUT + c;
    *(float4*)o       = make_float4(a[0] * inn + bA.x, a[1] * inn + bA.y,
                                    a[2] * inn + bA.z, a[3] * inn + bA.w);
    *(float4*)(o + 4) = make_float4(a[4] * inn + bB.x, a[5] * inn + bB.y,
                                    a[6] * inn + bB.z, a[7] * inn + bB.w);
}

extern "C" void kernel_launch(void* const* d_in, const int* in_sizes, int n_in,
                              void* d_out, int out_size, void* d_ws, size_t ws_size,
                              hipStream_t stream) {
    const float* feat = (const float*)d_in[0];
    const float* W1   = (const float*)d_in[1];
    const float* b1   = (const float*)d_in[2];
    const float* W2   = (const float*)d_in[3];
    const float* b2   = (const float*)d_in[4];
    const void*  srcp = (const void*)d_in[5];
    const void*  dstp = (const void*)d_in[6];
    const int    E    = in_sizes[5];
    float* out = (float*)d_out;

    char* w = (char*)d_ws;
    size_t off = 0;
    auto alloc = [&](size_t bytes) -> void* {
        off = (off + 255) & ~(size_t)255;
        void* p = w + off;
        off += bytes;
        return p;
    };
    int*   hist    = (int*)alloc((size_t)NBUCK * NB * 4);
    int*   bsum    = (int*)alloc((size_t)NBUCK * 4);
    int*   bb      = (int*)alloc((size_t)(NBUCK + 1) * 4);
    int*   rp      = (int*)alloc((size_t)(N_NODES + 1) * 4);
    unsigned int* spart = (unsigned int*)alloc((size_t)NB * NBINS8 * 4);
    unsigned int* tmp   = (unsigned int*)alloc((size_t)E * 4);
    int*   esrc    = (int*)alloc((size_t)E * 4);
    float* onorm   = (float*)alloc((size_t)N_NODES * 4);
    float* innorm  = (float*)alloc((size_t)N_NODES * 4);
    _Float16* W1T  = (_Float16*)alloc((size_t)IN_SIZE * HID * 2);
    _Float16* W2T  = (_Float16*)alloc((size_t)HID * OUT * 2);
    _Float16* X1   = (_Float16*)alloc((size_t)N_NODES * HID * 2);
    _Float16* X2   = (_Float16*)alloc((size_t)N_NODES * OUT * 2);
    (void)ws_size; (void)n_in; (void)out_size;

    const int EPB = (E + NB - 1) / NB;
    const int WTB = (IN_SIZE * HID + HID * OUT + 255) / 256;

    // CSR build — no global atomics anywhere
    k_hist_wt<<<NB + WTB, 256, 0, stream>>>(srcp, dstp, hist, spart, E, EPB, W1, W1T, W2, W2T);
    k_scanA<<<NBUCK, 256, 0, stream>>>(hist, bsum);
    k_scanB<<<1, 512, 0, stream>>>(bsum, bb);
    k_cscatter<<<NB, 256, 0, stream>>>(srcp, dstp, hist, bb, tmp, E, EPB);
    k_fine<<<NBUCK, 256, 0, stream>>>(tmp, bb, spart, rp, esrc, innorm, onorm);

    // dense + aggregation pipeline (gemm2 fused into agg1 epilogue)
    k_gemm1_mfma<<<(N_NODES + 63) / 64, 256, 0, stream>>>(feat, W1T, onorm, X1);
    k_agg1_fused<<<(N_NODES + 15) / 16, 256, 0, stream>>>(X1, rp, esrc, innorm, onorm, b1, W2T, X2);
    k_agg2<<<(N_NODES + 31) / 32, 256, 0, stream>>>(X2, rp, esrc, innorm, b2, out);
}